// Round 1
// baseline (50488.870 us; speedup 1.0000x reference)
//
#include <hip/hip_runtime.h>
#include <hip/hip_cooperative_groups.h>

namespace cg = cooperative_groups;

#define BB 256
#define TT 512
#define HH 512
#define G4 2048
#define BM 32           // batch rows per wg
#define BJ 8            // h-columns per wg
#define BN 32           // Wh cols per wg = 4*BJ (i,f,g,o)
#define NB (BB/BM)      // 8
#define NJ (HH/BJ)      // 64
#define NWG (NB*NJ)     // 512
#define NTHR 256

__device__ __forceinline__ float fsig(float x) {
    float e = exp2f(fminf(-1.44269504f * x, 80.f));
    return 1.f / (1.f + e);
}
__device__ __forceinline__ float ftanh(float x) {
    float e = exp2f(fminf(-2.88539008f * x, 80.f));
    return (1.f - e) / (1.f + e);
}

__global__ __launch_bounds__(NTHR, 2)
void lstm_fused(const float* __restrict__ x, const float* __restrict__ Wi,
                const float* __restrict__ Wh, const float* __restrict__ bias,
                const float* __restrict__ lns, const float* __restrict__ lnb,
                const float* __restrict__ Wd, const float* __restrict__ bd,
                float* __restrict__ out, float* __restrict__ hbuf)
{
    cg::grid_group grid = cg::this_grid();
    extern __shared__ float smem[];
    float* sWh = smem;            // [512][32]
    float* sWi = sWh + HH * BN;   // [3][32]
    float* sB  = sWi + 3 * BN;    // [32]
    float* sZ  = sB + BN;         // [32][33] padded

    const int bid = blockIdx.x;
    const int mb  = bid / NJ;     // 0..7
    const int nj  = bid % NJ;     // 0..63
    const int tid = threadIdx.x;
    const int row0 = mb * BM;

    // ---- one-time LDS staging of this wg's weight slices ----
    for (int idx = tid; idx < HH * BN; idx += NTHR) {
        int k = idx >> 5, lc = idx & 31;
        int gcol = ((lc >> 3) << 9) + (nj << 3) + (lc & 7);  // gate*512 + nj*8 + jj
        sWh[idx] = Wh[(size_t)k * G4 + gcol];
    }
    for (int idx = tid; idx < 3 * BN; idx += NTHR) {
        int f = idx >> 5, lc = idx & 31;
        int gcol = ((lc >> 3) << 9) + (nj << 3) + (lc & 7);
        sWi[idx] = Wi[(size_t)f * G4 + gcol];
    }
    if (tid < BN) {
        int gcol = ((tid >> 3) << 9) + (nj << 3) + (tid & 7);
        sB[tid] = bias[gcol];
    }
    __syncthreads();

    // matmul map: thread -> 1 row x 4 cols.   gate map: thread -> (row rA, col jA)
    const int rp = tid >> 3;          // 0..31
    const int cq = tid & 7;           // 0..7
    const int lc = cq * 4;
    float creg = 0.f;                 // persistent cell state for (rA=rp, jA=cq)

    for (int it = 0; it <= TT; ++it) {
        const float* hin = hbuf + (size_t)(it & 1) * (BB * HH);
        float*      hout = hbuf + (size_t)((it + 1) & 1) * (BB * HH);

        if (it < TT) {
            // z = xg (+ h @ Wh for it>0)
            float acc[4];
            const float* xr = x + ((size_t)(row0 + rp) * TT + it) * 3;
            float x0 = xr[0], x1 = xr[1], x2 = xr[2];
            #pragma unroll
            for (int q = 0; q < 4; ++q) {
                acc[q] = sB[lc + q] + x0 * sWi[lc + q] + x1 * sWi[BN + lc + q]
                       + x2 * sWi[2 * BN + lc + q];
            }
            if (it > 0) {
                const float* hp = hin + (size_t)(row0 + rp) * HH;
                for (int k = 0; k < HH; k += 4) {
                    const float4 hv = *(const float4*)(hp + k);
                    const float ha[4] = {hv.x, hv.y, hv.z, hv.w};
                    #pragma unroll
                    for (int u = 0; u < 4; ++u) {
                        const float4 w = *(const float4*)(sWh + (k + u) * BN + lc);
                        acc[0] = fmaf(ha[u], w.x, acc[0]);
                        acc[1] = fmaf(ha[u], w.y, acc[1]);
                        acc[2] = fmaf(ha[u], w.z, acc[2]);
                        acc[3] = fmaf(ha[u], w.w, acc[3]);
                    }
                }
            }
            #pragma unroll
            for (int q = 0; q < 4; ++q) sZ[rp * 33 + lc + q] = acc[q];
            __syncthreads();

            // gate update: thread owns (row rp, hidden col jA=cq)
            float zi = sZ[rp * 33 +      cq];
            float zf = sZ[rp * 33 +  8 + cq];
            float zg = sZ[rp * 33 + 16 + cq];
            float zo = sZ[rp * 33 + 24 + cq];
            float ig = fsig(zi), fg = fsig(zf), gg = ftanh(zg), og = fsig(zo);
            creg = fg * creg + ig * gg;
            float hval = og * ftanh(creg);
            hout[(size_t)(row0 + rp) * HH + (nj << 3) + cq] = hval;
        }

        // rotating output head: LN -> relu -> @Wd for t = it-1 (h_t is in hin)
        if (it >= 1 && nj == ((it - 1) & (NJ - 1))) {
            const int t = it - 1;
            const int orow = tid >> 3, part = tid & 7;
            const float* hr = hin + (size_t)(row0 + orow) * HH + part * 64;
            float s = 0.f, ss = 0.f;
            #pragma unroll
            for (int k = 0; k < 64; k += 4) {
                float4 v = *(const float4*)(hr + k);
                s  += v.x + v.y + v.z + v.w;
                ss += v.x * v.x + v.y * v.y + v.z * v.z + v.w * v.w;
            }
            #pragma unroll
            for (int d = 1; d < 8; d <<= 1) { s += __shfl_xor(s, d); ss += __shfl_xor(ss, d); }
            float mu   = s * (1.f / 512.f);
            float rstd = rsqrtf(ss * (1.f / 512.f) - mu * mu + 1e-6f);
            float d0 = 0.f, d1 = 0.f, d2 = 0.f;
            for (int k = 0; k < 64; ++k) {
                int col = part * 64 + k;
                float v = (hr[k] - mu) * rstd * lns[col] + lnb[col];
                v = fmaxf(v, 0.f);
                d0 = fmaf(v, Wd[col * 3 + 0], d0);
                d1 = fmaf(v, Wd[col * 3 + 1], d1);
                d2 = fmaf(v, Wd[col * 3 + 2], d2);
            }
            #pragma unroll
            for (int d = 1; d < 8; d <<= 1) {
                d0 += __shfl_xor(d0, d); d1 += __shfl_xor(d1, d); d2 += __shfl_xor(d2, d);
            }
            if (part == 0) {
                size_t o = ((size_t)(row0 + orow) * TT + t) * 3;
                out[o + 0] = d0 + bd[0];
                out[o + 1] = d1 + bd[1];
                out[o + 2] = d2 + bd[2];
            }
        }

        if (it < TT) grid.sync();
    }
}

extern "C" void kernel_launch(void* const* d_in, const int* in_sizes, int n_in,
                              void* d_out, int out_size, void* d_ws, size_t ws_size,
                              hipStream_t stream) {
    const float* x   = (const float*)d_in[0];
    const float* Wi  = (const float*)d_in[1];
    const float* Wh  = (const float*)d_in[2];
    const float* b   = (const float*)d_in[3];
    const float* lns = (const float*)d_in[4];
    const float* lnb = (const float*)d_in[5];
    const float* Wd  = (const float*)d_in[6];
    const float* bd  = (const float*)d_in[7];
    float* out  = (float*)d_out;
    float* hbuf = (float*)d_ws;   // [2][256][512] fp32 = 1 MB

    size_t smem = (size_t)(HH * BN + 3 * BN + BN + 32 * 33) * sizeof(float); // ~70 KB
    hipFuncSetAttribute((const void*)lstm_fused,
                        hipFuncAttributeMaxDynamicSharedMemorySize, (int)smem);

    void* args[] = { (void*)&x, (void*)&Wi, (void*)&Wh, (void*)&b, (void*)&lns,
                     (void*)&lnb, (void*)&Wd, (void*)&bd, (void*)&out, (void*)&hbuf };
    hipLaunchCooperativeKernel((void*)lstm_fused, dim3(NWG), dim3(NTHR),
                               args, (unsigned int)smem, stream);
}

// Round 2
// 18559.914 us; speedup vs baseline: 2.7203x; 2.7203x over previous
//
#include <hip/hip_runtime.h>

#define BB 256
#define TT 512
#define HH 512
#define G4 2048
#define BM 32           // batch rows per wg
#define BJ 16           // hidden cols per wg
#define NB 8            // 256/32
#define NJ 32           // 512/16
#define NWG 256
#define NTHR 512

__device__ __forceinline__ float fsig(float x) {
    float e = exp2f(fminf(-1.44269504f * x, 80.f));
    return 1.f / (1.f + e);
}
__device__ __forceinline__ float ftanh(float x) {
    float e = exp2f(fminf(-2.88539008f * x, 80.f));
    return (1.f - e) / (1.f + e);
}

// ---- 2-level sense-reversing grid barrier -------------------------------
// bar layout (unsigned, 256B-padded slots): [0..7]*64 group counters,
// [8*64] root counter, [9*64] generation. Zeroed by hipMemsetAsync per call.
__device__ __forceinline__ void grid_barrier(unsigned* bar) {
    __syncthreads();                       // all wg mem ops drained (vmcnt0)
    if (threadIdx.x == 0) {
        unsigned* gen = bar + 9 * 64;
        unsigned old = __hip_atomic_load(gen, __ATOMIC_RELAXED, __HIP_MEMORY_SCOPE_AGENT);
        __threadfence();                   // release: h writes -> device visible
        const int gi = blockIdx.x & 7;
        unsigned a = __hip_atomic_fetch_add(bar + gi * 64, 1u,
                                            __ATOMIC_RELAXED, __HIP_MEMORY_SCOPE_AGENT);
        bool done = false;
        if (a == (NWG / 8 - 1)) {          // last in group
            __hip_atomic_store(bar + gi * 64, 0u, __ATOMIC_RELAXED, __HIP_MEMORY_SCOPE_AGENT);
            unsigned r = __hip_atomic_fetch_add(bar + 8 * 64, 1u,
                                                __ATOMIC_RELAXED, __HIP_MEMORY_SCOPE_AGENT);
            if (r == 7u) {                 // last group
                __hip_atomic_store(bar + 8 * 64, 0u, __ATOMIC_RELAXED, __HIP_MEMORY_SCOPE_AGENT);
                __hip_atomic_fetch_add(gen, 1u, __ATOMIC_RELAXED, __HIP_MEMORY_SCOPE_AGENT);
                done = true;
            }
        }
        if (!done) {
            while (__hip_atomic_load(gen, __ATOMIC_RELAXED, __HIP_MEMORY_SCOPE_AGENT) == old)
                __builtin_amdgcn_s_sleep(1);
        }
        __threadfence();                   // acquire: see remote h writes
    }
    __syncthreads();
}

__global__ __launch_bounds__(NTHR, 1)
void lstm_fused(const float* __restrict__ x, const float* __restrict__ Wi,
                const float* __restrict__ Wh, const float* __restrict__ bias,
                const float* __restrict__ lns, const float* __restrict__ lnb,
                const float* __restrict__ Wd, const float* __restrict__ bd,
                float* __restrict__ out, float* __restrict__ hbuf, unsigned* bar)
{
    extern __shared__ float smem[];
    float* sWh = smem;                 // [512][64]: sWh[k][cq*4+g] = Wh[k][g*512+nj*16+cq]
    float* sWi = sWh + HH * 64;        // [3][64]
    float* sB  = sWi + 3 * 64;         // [64]

    const int bid = blockIdx.x;
    const int mb  = bid >> 5;          // 0..7
    const int nj  = bid & 31;          // 0..31
    const int tid = threadIdx.x;
    const int row0 = mb * BM;

    // one-time LDS staging: gate-interleaved Wh slice
    for (int idx = tid; idx < HH * 64; idx += NTHR) {
        int k = idx >> 6, lc = idx & 63;
        int gcol = ((lc & 3) << 9) + (nj << 4) + (lc >> 2);   // gate*512 + j
        sWh[idx] = Wh[(size_t)k * G4 + gcol];
    }
    if (tid < 3 * 64) {
        int f = tid >> 6, lc = tid & 63;
        int gcol = ((lc & 3) << 9) + (nj << 4) + (lc >> 2);
        sWi[tid] = Wi[(size_t)f * G4 + gcol];
    }
    if (tid < 64) {
        int gcol = ((tid & 3) << 9) + (nj << 4) + (tid >> 2);
        sB[tid] = bias[gcol];
    }
    __syncthreads();

    const int rp = tid >> 4;           // 0..31 row
    const int cq = tid & 15;           // 0..15 hidden col
    const int lc = cq << 2;
    float creg = 0.f;

    for (int it = 0; it <= TT; ++it) {
        const float* hin = hbuf + (size_t)(it & 1) * (BB * HH);
        float*      hout = hbuf + (size_t)((it + 1) & 1) * (BB * HH);

        // rotating output head for t = it-1 (reads hin, fenced by barrier)
        if (it >= 1 && nj == ((it - 1) & 31)) {
            const int t = it - 1;
            const int orow = tid >> 4, part = tid & 15;
            const float* hr = hin + (size_t)(row0 + orow) * HH + part * 32;
            float s = 0.f, ss = 0.f;
            #pragma unroll
            for (int k = 0; k < 32; k += 4) {
                float4 v = *(const float4*)(hr + k);
                s  += v.x + v.y + v.z + v.w;
                ss += v.x * v.x + v.y * v.y + v.z * v.z + v.w * v.w;
            }
            #pragma unroll
            for (int d = 1; d < 16; d <<= 1) { s += __shfl_xor(s, d); ss += __shfl_xor(ss, d); }
            float mu   = s * (1.f / 512.f);
            float rstd = rsqrtf(ss * (1.f / 512.f) - mu * mu + 1e-6f);
            float d0 = 0.f, d1 = 0.f, d2 = 0.f;
            #pragma unroll 8
            for (int k = 0; k < 32; ++k) {
                int col = part * 32 + k;
                float v = (hr[k] - mu) * rstd * lns[col] + lnb[col];
                v = fmaxf(v, 0.f);
                d0 = fmaf(v, Wd[col * 3 + 0], d0);
                d1 = fmaf(v, Wd[col * 3 + 1], d1);
                d2 = fmaf(v, Wd[col * 3 + 2], d2);
            }
            #pragma unroll
            for (int d = 1; d < 16; d <<= 1) {
                d0 += __shfl_xor(d0, d); d1 += __shfl_xor(d1, d); d2 += __shfl_xor(d2, d);
            }
            if (part == 0) {
                size_t o = ((size_t)(row0 + orow) * TT + t) * 3;
                out[o + 0] = d0 + bd[0];
                out[o + 1] = d1 + bd[1];
                out[o + 2] = d2 + bd[2];
            }
        }

        if (it < TT) {
            // z(i,f,g,o) for (row rp, hidden col nj*16+cq) — no exchange needed
            float acc[4];
            const float* xr = x + ((size_t)(row0 + rp) * TT + it) * 3;
            float x0 = xr[0], x1 = xr[1], x2 = xr[2];
            #pragma unroll
            for (int g = 0; g < 4; ++g)
                acc[g] = sB[lc + g] + x0 * sWi[lc + g] + x1 * sWi[64 + lc + g]
                       + x2 * sWi[128 + lc + g];
            if (it > 0) {
                const float* hp = hin + (size_t)(row0 + rp) * HH;
                #pragma unroll 4
                for (int k = 0; k < HH; k += 4) {
                    const float4 hv = *(const float4*)(hp + k);
                    const float ha[4] = {hv.x, hv.y, hv.z, hv.w};
                    #pragma unroll
                    for (int u = 0; u < 4; ++u) {
                        const float4 w = *(const float4*)(sWh + (size_t)(k + u) * 64 + lc);
                        acc[0] = fmaf(ha[u], w.x, acc[0]);
                        acc[1] = fmaf(ha[u], w.y, acc[1]);
                        acc[2] = fmaf(ha[u], w.z, acc[2]);
                        acc[3] = fmaf(ha[u], w.w, acc[3]);
                    }
                }
            }
            float ig = fsig(acc[0]), fg = fsig(acc[1]);
            float gg = ftanh(acc[2]), og = fsig(acc[3]);
            creg = fg * creg + ig * gg;
            float hval = og * ftanh(creg);
            hout[(size_t)(row0 + rp) * HH + (nj << 4) + cq] = hval;
            grid_barrier(bar);
        }
    }
}

extern "C" void kernel_launch(void* const* d_in, const int* in_sizes, int n_in,
                              void* d_out, int out_size, void* d_ws, size_t ws_size,
                              hipStream_t stream) {
    const float* x   = (const float*)d_in[0];
    const float* Wi  = (const float*)d_in[1];
    const float* Wh  = (const float*)d_in[2];
    const float* b   = (const float*)d_in[3];
    const float* lns = (const float*)d_in[4];
    const float* lnb = (const float*)d_in[5];
    const float* Wd  = (const float*)d_in[6];
    const float* bd  = (const float*)d_in[7];
    float* out  = (float*)d_out;
    float* hbuf = (float*)d_ws;                               // 2*256*512*4 = 1 MB
    unsigned* bar = (unsigned*)((char*)d_ws + (size_t)2 * BB * HH * 4);

    hipMemsetAsync(bar, 0, 10 * 64 * sizeof(unsigned), stream);

    size_t smem = (size_t)(HH * 64 + 3 * 64 + 64) * sizeof(float);  // ~129 KB
    hipFuncSetAttribute((const void*)lstm_fused,
                        hipFuncAttributeMaxDynamicSharedMemorySize, (int)smem);

    void* args[] = { (void*)&x, (void*)&Wi, (void*)&Wh, (void*)&b, (void*)&lns,
                     (void*)&lnb, (void*)&Wd, (void*)&bd, (void*)&out, (void*)&hbuf,
                     (void*)&bar };
    hipLaunchCooperativeKernel((void*)lstm_fused, dim3(NWG), dim3(NTHR),
                               args, (unsigned int)smem, stream);
}

// Round 3
// 13744.489 us; speedup vs baseline: 3.6734x; 1.3504x over previous
//
#include <hip/hip_runtime.h>

#define BB 256
#define TT 512
#define HH 512
#define G4 2048
#define NTHR 512
#define NWG 256
#define RPW 64                  // rows per wg (group rows)
#define CPW 32                  // gate-cols per wg = 8 hid x 4 gates
#define NJ 64                   // col-slices per group
#define NG 4                    // row groups
#define PLANE (BB*HH)           // 131072 elems per bf16 plane
#define SB_PL (CPW*HH)          // 16384 elems per B LDS plane

typedef __attribute__((ext_vector_type(8))) short short8;
typedef __attribute__((ext_vector_type(4))) float f32x4;

__device__ __forceinline__ ushort bf16r(float f) {          // RNE fp32->bf16
    unsigned u = __float_as_uint(f);
    return (ushort)((u + 0x7FFFu + ((u >> 16) & 1u)) >> 16);
}
__device__ __forceinline__ float bf16f(ushort s) {
    return __uint_as_float(((unsigned)s) << 16);
}
__device__ __forceinline__ float fsig(float x) {
    float e = exp2f(fminf(-1.44269504f * x, 80.f));
    return 1.f / (1.f + e);
}
__device__ __forceinline__ float ftanh(float x) {
    float e = exp2f(fminf(-2.88539008f * x, 80.f));
    return (1.f - e) / (1.f + e);
}

// group-local barrier: 64 wgs per group. bar: cnt at [g*64], gen at [(4+g)*64]
__device__ __forceinline__ void group_barrier(unsigned* bar, int g) {
    __syncthreads();
    if (threadIdx.x == 0) {
        unsigned* cnt = bar + g * 64;
        unsigned* gen = bar + (NG + g) * 64;
        unsigned old = __hip_atomic_load(gen, __ATOMIC_RELAXED, __HIP_MEMORY_SCOPE_AGENT);
        __threadfence();                      // release h-plane writes
        unsigned a = __hip_atomic_fetch_add(cnt, 1u, __ATOMIC_RELAXED, __HIP_MEMORY_SCOPE_AGENT);
        if (a == 63u) {
            __hip_atomic_store(cnt, 0u, __ATOMIC_RELAXED, __HIP_MEMORY_SCOPE_AGENT);
            __hip_atomic_fetch_add(gen, 1u, __ATOMIC_RELAXED, __HIP_MEMORY_SCOPE_AGENT);
        } else {
            while (__hip_atomic_load(gen, __ATOMIC_RELAXED, __HIP_MEMORY_SCOPE_AGENT) == old)
                __builtin_amdgcn_s_sleep(1);
        }
        __threadfence();                      // acquire remote h-plane writes
    }
    __syncthreads();
}

__global__ __launch_bounds__(NTHR, 1)
void lstm_mfma(const float* __restrict__ x, const float* __restrict__ Wi,
               const float* __restrict__ Wh, const float* __restrict__ bias,
               const float* __restrict__ lns, const float* __restrict__ lnb,
               const float* __restrict__ Wd, const float* __restrict__ bd,
               float* __restrict__ out, ushort* __restrict__ planes, unsigned* bar)
{
    extern __shared__ char smem[];
    short* sB    = (short*)smem;                    // [3][32 cols][512 k], swizzled, 96KB
    float* sWi   = (float*)(smem + 3 * SB_PL * 2);  // [3][32]
    float* sBias = sWi + 3 * CPW;                   // [32]
    float* sWd   = sBias + CPW;                     // [512*3]

    const int bid  = blockIdx.x;
    const int gidx = bid >> 6;          // row group 0..3
    const int nj   = bid & 63;          // col slice 0..63
    const int tid  = threadIdx.x;
    const int grow0 = gidx * RPW;       // first row of group
    const int hid0  = nj * 8;           // first hidden col of slice

    // ---- prologue: decompose Wh slice into 3 bf16 LDS planes [col][k] ----
    for (int i = tid; i < CPW * (HH / 8); i += NTHR) {   // 2048 iters
        int lc = i >> 6, kg = i & 63, k0 = kg * 8;
        int gc = ((lc & 3) << 9) + hid0 + (lc >> 2);     // gate*512 + hid
        short8 vh, vm, vl;
        #pragma unroll
        for (int j = 0; j < 8; ++j) {
            float w = Wh[(size_t)(k0 + j) * G4 + gc];
            ushort c0 = bf16r(w);  float r1 = w - bf16f(c0);
            ushort c1 = bf16r(r1); float r2 = r1 - bf16f(c1);
            ushort c2 = bf16r(r2);
            vh[j] = (short)c0; vm[j] = (short)c1; vl[j] = (short)c2;
        }
        int base = lc * HH + (k0 ^ ((lc & 7) << 3));     // XOR bank swizzle
        *(short8*)&sB[base]            = vh;
        *(short8*)&sB[SB_PL + base]    = vm;
        *(short8*)&sB[2 * SB_PL + base] = vl;
    }
    if (tid < CPW) {
        int gc = ((tid & 3) << 9) + hid0 + (tid >> 2);
        sBias[tid] = bias[gc];
        for (int f = 0; f < 3; ++f) sWi[f * CPW + tid] = Wi[(size_t)f * G4 + gc];
    }
    for (int i = tid; i < HH * 3; i += NTHR) sWd[i] = Wd[i];
    __syncthreads();

    // wave->tile map: 8 waves = 4 row-tiles x 2 col-tiles of 16x16
    const int wave = tid >> 6, lane = tid & 63;
    const int tr = wave >> 1, tc = wave & 1;
    const int lcl   = tc * 16 + (lane & 15);        // local gate-col 0..31
    const int rbase = tr * 16 + ((lane >> 4) << 2); // C row base (+q)
    const int hid_g = hid0 + (lcl >> 2);
    const int myp   = lane & 3;
    const int qbase = lane & ~3;

    float creg[4] = {0.f, 0.f, 0.f, 0.f};

    for (int it = 0; it <= TT; ++it) {
        const ushort* Pin = planes + (size_t)(it & 1) * (3 * PLANE);
        ushort*      Pout = planes + (size_t)((it + 1) & 1) * (3 * PLANE);

        // ---- output head for t = it-1: wave 0, one row per wg ----
        if (it >= 1 && wave == 0) {
            const int t = it - 1;
            const int row_h = grow0 + nj;
            size_t off = (size_t)row_h * HH + lane * 8;
            short8 vh = *(const short8*)(Pin + off);
            short8 vm = *(const short8*)(Pin + PLANE + off);
            short8 vl = *(const short8*)(Pin + 2 * PLANE + off);
            float h[8]; float s = 0.f, ss = 0.f;
            #pragma unroll
            for (int j = 0; j < 8; ++j) {
                h[j] = bf16f((ushort)vh[j]) + bf16f((ushort)vm[j]) + bf16f((ushort)vl[j]);
                s += h[j]; ss += h[j] * h[j];
            }
            #pragma unroll
            for (int d = 1; d < 64; d <<= 1) { s += __shfl_xor(s, d); ss += __shfl_xor(ss, d); }
            float mu = s * (1.f / 512.f);
            float rstd = rsqrtf(ss * (1.f / 512.f) - mu * mu + 1e-6f);
            float d0 = 0.f, d1 = 0.f, d2 = 0.f;
            #pragma unroll
            for (int j = 0; j < 8; ++j) {
                int col = lane * 8 + j;
                float y = (h[j] - mu) * rstd * lns[col] + lnb[col];
                y = fmaxf(y, 0.f);
                d0 = fmaf(y, sWd[col * 3 + 0], d0);
                d1 = fmaf(y, sWd[col * 3 + 1], d1);
                d2 = fmaf(y, sWd[col * 3 + 2], d2);
            }
            #pragma unroll
            for (int d = 1; d < 64; d <<= 1) {
                d0 += __shfl_xor(d0, d); d1 += __shfl_xor(d1, d); d2 += __shfl_xor(d2, d);
            }
            if (lane == 0) {
                size_t o = ((size_t)row_h * TT + t) * 3;
                out[o + 0] = d0 + bd[0];
                out[o + 1] = d1 + bd[1];
                out[o + 2] = d2 + bd[2];
            }
        }

        if (it < TT) {
            // ---- acc init = xg (x @ Wi + b), fp32 exact ----
            f32x4 acc;
            #pragma unroll
            for (int q = 0; q < 4; ++q) {
                int r = grow0 + rbase + q;
                const float* xp = x + ((size_t)r * TT + it) * 3;
                acc[q] = sBias[lcl] + xp[0] * sWi[lcl] + xp[1] * sWi[CPW + lcl]
                       + xp[2] * sWi[2 * CPW + lcl];
            }
            // ---- h @ Wh via 6-pass split-bf16 MFMA over K=512 ----
            if (it > 0) {
                const ushort* p0 = Pin;
                const ushort* p1 = Pin + PLANE;
                const ushort* p2 = Pin + 2 * PLANE;
                const int arow = grow0 + tr * 16 + (lane & 15);
                const int kb = (lane >> 4) * 8;
                const int bcol = lcl * HH;
                const int bx = (lcl & 7) << 3;
                #pragma unroll 4
                for (int kc = 0; kc < 16; ++kc) {
                    int ka = kc * 32 + kb;
                    size_t aoff = (size_t)arow * HH + ka;
                    short8 Ah = *(const short8*)(p0 + aoff);
                    short8 Am = *(const short8*)(p1 + aoff);
                    short8 Al = *(const short8*)(p2 + aoff);
                    int bo = bcol + (ka ^ bx);
                    short8 Bh = *(const short8*)&sB[bo];
                    short8 Bm = *(const short8*)&sB[SB_PL + bo];
                    short8 Bl = *(const short8*)&sB[2 * SB_PL + bo];
                    acc = __builtin_amdgcn_mfma_f32_16x16x32_bf16(Ah, Bh, acc, 0, 0, 0);
                    acc = __builtin_amdgcn_mfma_f32_16x16x32_bf16(Ah, Bm, acc, 0, 0, 0);
                    acc = __builtin_amdgcn_mfma_f32_16x16x32_bf16(Am, Bh, acc, 0, 0, 0);
                    acc = __builtin_amdgcn_mfma_f32_16x16x32_bf16(Ah, Bl, acc, 0, 0, 0);
                    acc = __builtin_amdgcn_mfma_f32_16x16x32_bf16(Am, Bm, acc, 0, 0, 0);
                    acc = __builtin_amdgcn_mfma_f32_16x16x32_bf16(Al, Bh, acc, 0, 0, 0);
                }
            }
            // ---- gather 4 gates across the lane quad (cols interleaved hid*4+gate)
            float zi[4], zf[4], zg[4], zo[4];
            #pragma unroll
            for (int q = 0; q < 4; ++q) {
                zi[q] = __shfl(acc[q], qbase + 0);
                zf[q] = __shfl(acc[q], qbase + 1);
                zg[q] = __shfl(acc[q], qbase + 2);
                zo[q] = __shfl(acc[q], qbase + 3);
            }
            #pragma unroll
            for (int q = 0; q < 4; ++q) {
                float ig = fsig(zi[q]), fg = fsig(zf[q]);
                float gv = ftanh(zg[q]), og = fsig(zo[q]);
                creg[q] = fg * creg[q] + ig * gv;
                float hv = og * ftanh(creg[q]);
                ushort c0 = bf16r(hv);  float r1 = hv - bf16f(c0);
                ushort c1 = bf16r(r1);  float r2 = r1 - bf16f(c1);
                ushort c2 = bf16r(r2);
                if (myp < 3) {
                    ushort w = (myp == 0) ? c0 : ((myp == 1) ? c1 : c2);
                    int r = grow0 + rbase + q;
                    Pout[(size_t)myp * PLANE + (size_t)r * HH + hid_g] = w;
                }
            }
            group_barrier(bar, gidx);
        }
    }
}

extern "C" void kernel_launch(void* const* d_in, const int* in_sizes, int n_in,
                              void* d_out, int out_size, void* d_ws, size_t ws_size,
                              hipStream_t stream) {
    const float* x   = (const float*)d_in[0];
    const float* Wi  = (const float*)d_in[1];
    const float* Wh  = (const float*)d_in[2];
    const float* b   = (const float*)d_in[3];
    const float* lns = (const float*)d_in[4];
    const float* lnb = (const float*)d_in[5];
    const float* Wd  = (const float*)d_in[6];
    const float* bd  = (const float*)d_in[7];
    float* out = (float*)d_out;

    ushort* planes = (ushort*)d_ws;                           // 2*3*131072*2B = 1.5MB
    unsigned* bar  = (unsigned*)((char*)d_ws + (size_t)2 * 3 * PLANE * 2);

    hipMemsetAsync(bar, 0, 2 * NG * 64 * sizeof(unsigned), stream);

    size_t smem = (size_t)3 * SB_PL * 2 + (3 * CPW + CPW + HH * 3) * sizeof(float); // ~105KB
    hipFuncSetAttribute((const void*)lstm_mfma,
                        hipFuncAttributeMaxDynamicSharedMemorySize, (int)smem);

    void* args[] = { (void*)&x, (void*)&Wi, (void*)&Wh, (void*)&b, (void*)&lns,
                     (void*)&lnb, (void*)&Wd, (void*)&bd, (void*)&out,
                     (void*)&planes, (void*)&bar };
    hipLaunchCooperativeKernel((void*)lstm_mfma, dim3(NWG), dim3(NTHR),
                               args, (unsigned int)smem, stream);
}

// Round 5
// 10481.812 us; speedup vs baseline: 4.8168x; 1.3113x over previous
//
#include <hip/hip_runtime.h>

#define BB 256
#define TT 512
#define HH 512
#define G4 2048
#define WPL (G4*HH)         // 1048576 elems per Wh bf16 plane
#define PLANE (BB*HH)       // 131072 elems per h bf16 plane

typedef __attribute__((ext_vector_type(8))) short short8;
typedef __attribute__((ext_vector_type(4))) float f32x4;

__device__ __forceinline__ ushort bf16r(float f) {          // RNE fp32->bf16
    unsigned u = __float_as_uint(f);
    return (ushort)((u + 0x7FFFu + ((u >> 16) & 1u)) >> 16);
}
__device__ __forceinline__ float bf16f(ushort s) {
    return __uint_as_float(((unsigned)s) << 16);
}
__device__ __forceinline__ float fsig(float x) {
    float e = exp2f(fminf(-1.44269504f * x, 80.f));
    return 1.f / (1.f + e);
}
__device__ __forceinline__ float ftanh(float x) {
    float e = exp2f(fminf(-2.88539008f * x, 80.f));
    return (1.f - e) / (1.f + e);
}

// ---- one-time: decompose Wh fp32 -> 3 bf16 planes, layout [gcol][k] ----
__global__ __launch_bounds__(256)
void wprep_kernel(const float* __restrict__ Wh, ushort* __restrict__ whp) {
    const int gcol = blockIdx.x * 256 + threadIdx.x;   // 2048 total
    for (int k0 = 0; k0 < HH; k0 += 8) {
        short8 vh, vm, vl;
        #pragma unroll
        for (int j = 0; j < 8; ++j) {
            float w = Wh[(size_t)(k0 + j) * G4 + gcol];
            ushort c0 = bf16r(w);  float r1 = w - bf16f(c0);
            ushort c1 = bf16r(r1); float r2 = r1 - bf16f(c1);
            ushort c2 = bf16r(r2);
            vh[j] = (short)c0; vm[j] = (short)c1; vl[j] = (short)c2;
        }
        size_t base = (size_t)gcol * HH + k0;
        *(short8*)&whp[base]           = vh;
        *(short8*)&whp[WPL + base]     = vm;
        *(short8*)&whp[2 * WPL + base] = vl;
    }
}

// ---- one step: z = xg + h(t-1)@Wh, gates, write h(t) planes + c.
// Also computes the LN->relu->Wd head for h(t-1) (wave 7, one row per wg).
// t ranges 0..512; t==512 does head only.
__global__ __launch_bounds__(512, 1)
void lstm_step(const float* __restrict__ x, const float* __restrict__ Wi,
               const float* __restrict__ bias, const float* __restrict__ lns,
               const float* __restrict__ lnb, const float* __restrict__ Wd,
               const float* __restrict__ bd, const ushort* __restrict__ whp,
               ushort* __restrict__ planes, float* __restrict__ cst,
               float* __restrict__ out, int t)
{
    extern __shared__ short sW[];          // [3][32][512] bf16, swizzled: 96 KB
    const int bid = blockIdx.x, tid = threadIdx.x;
    const int rg = bid & 3, cs = bid >> 2;     // 4 row-groups x 64 col-slices
    const int row0 = rg << 6;                  // 64 rows per wg

    // ---- stage this wg's W slice: 3 planes x 32 cols x 512 k ----
    if (t < TT) {
        for (int i = tid; i < 3 * 32 * 64; i += 512) {   // 16B granules
            int p = i >> 11, rem = i & 2047;
            int lc = rem >> 6, k0 = (rem & 63) << 3;
            int gc = ((lc & 3) << 9) + (cs << 3) + (lc >> 2);  // gate*512+hid
            short8 v = *(const short8*)&whp[(size_t)p * WPL + (size_t)gc * HH + k0];
            *(short8*)&sW[((p << 5) + lc) * HH + (k0 ^ ((lc & 7) << 3))] = v;
        }
    }
    __syncthreads();

    const int wave = tid >> 6, lane = tid & 63;

    // ---- output head for t-1 (row row0+cs), wave 7 ----
    if (t >= 1 && wave == 7) {
        const ushort* Pin = planes + (size_t)(t & 1) * (3 * PLANE);
        const int hrow = row0 + cs;
        const ushort* hp = Pin + (size_t)hrow * HH + lane * 8;
        short8 vh = *(const short8*)hp;
        short8 vm = *(const short8*)(hp + PLANE);
        short8 vl = *(const short8*)(hp + 2 * PLANE);
        float h[8]; float s = 0.f, ss = 0.f;
        #pragma unroll
        for (int j = 0; j < 8; ++j) {
            h[j] = bf16f((ushort)vh[j]) + bf16f((ushort)vm[j]) + bf16f((ushort)vl[j]);
            s += h[j]; ss += h[j] * h[j];
        }
        #pragma unroll
        for (int d = 1; d < 64; d <<= 1) { s += __shfl_xor(s, d); ss += __shfl_xor(ss, d); }
        float mu = s * (1.f / 512.f);
        float rstd = rsqrtf(ss * (1.f / 512.f) - mu * mu + 1e-6f);
        float d0 = 0.f, d1 = 0.f, d2 = 0.f;
        #pragma unroll
        for (int j = 0; j < 8; ++j) {
            int col = lane * 8 + j;
            float y = (h[j] - mu) * rstd * lns[col] + lnb[col];
            y = fmaxf(y, 0.f);
            d0 = fmaf(y, Wd[col * 3 + 0], d0);
            d1 = fmaf(y, Wd[col * 3 + 1], d1);
            d2 = fmaf(y, Wd[col * 3 + 2], d2);
        }
        #pragma unroll
        for (int d = 1; d < 64; d <<= 1) {
            d0 += __shfl_xor(d0, d); d1 += __shfl_xor(d1, d); d2 += __shfl_xor(d2, d);
        }
        if (lane == 0) {
            size_t o = ((size_t)hrow * TT + (t - 1)) * 3;
            out[o + 0] = d0 + bd[0];
            out[o + 1] = d1 + bd[1];
            out[o + 2] = d2 + bd[2];
        }
    }

    if (t < TT) {
        const int tr = wave & 3, tc = wave >> 2;       // 4 row-tiles x 2 col-tiles
        const int lcB  = (tc << 4) + (lane & 15);      // local gate-col 0..31
        const int swz  = (lcB & 7) << 3;
        const int kb   = (lane >> 4) << 3;
        const int rbase = (tr << 4) + ((lane >> 4) << 2);
        const int myp  = lane & 3, qb = lane & ~3;
        const int hid  = (cs << 3) + (tc << 2) + ((lane & 15) >> 2);
        const int gc   = ((lcB & 3) << 9) + (cs << 3) + (lcB >> 2);

        // xg = x@Wi + b (fp32 exact)
        f32x4 acc;
        {
            const float b0 = bias[gc], wi0 = Wi[gc], wi1 = Wi[G4 + gc], wi2 = Wi[2 * G4 + gc];
            #pragma unroll
            for (int q = 0; q < 4; ++q) {
                const float* xp = x + ((size_t)(row0 + rbase + q) * TT + t) * 3;
                acc[q] = b0 + xp[0] * wi0 + xp[1] * wi1 + xp[2] * wi2;
            }
        }
        // h(t-1) @ Wh : 6-pass split-bf16 MFMA over K=512
        if (t > 0) {
            const ushort* Pin = planes + (size_t)(t & 1) * (3 * PLANE);
            const ushort* a0 = Pin + (size_t)(row0 + (tr << 4) + (lane & 15)) * HH + kb;
            #pragma unroll 4
            for (int kc = 0; kc < 16; ++kc) {
                int ka = kc << 5;
                short8 Ah = *(const short8*)(a0 + ka);
                short8 Am = *(const short8*)(a0 + PLANE + ka);
                short8 Al = *(const short8*)(a0 + 2 * PLANE + ka);
                int ko = (ka + kb) ^ swz;
                short8 Bh = *(const short8*)&sW[(size_t)lcB * HH + ko];
                short8 Bm = *(const short8*)&sW[(size_t)(32 + lcB) * HH + ko];
                short8 Bl = *(const short8*)&sW[(size_t)(64 + lcB) * HH + ko];
                acc = __builtin_amdgcn_mfma_f32_16x16x32_bf16(Ah, Bh, acc, 0, 0, 0);
                acc = __builtin_amdgcn_mfma_f32_16x16x32_bf16(Am, Bh, acc, 0, 0, 0);
                acc = __builtin_amdgcn_mfma_f32_16x16x32_bf16(Ah, Bm, acc, 0, 0, 0);
                acc = __builtin_amdgcn_mfma_f32_16x16x32_bf16(Al, Bh, acc, 0, 0, 0);
                acc = __builtin_amdgcn_mfma_f32_16x16x32_bf16(Am, Bm, acc, 0, 0, 0);
                acc = __builtin_amdgcn_mfma_f32_16x16x32_bf16(Ah, Bl, acc, 0, 0, 0);
            }
        }
        // gather the 4 gates of this quad's (rows, hid)
        float zi[4], zf[4], zg[4], zo[4];
        #pragma unroll
        for (int q = 0; q < 4; ++q) {
            zi[q] = __shfl(acc[q], qb + 0);
            zf[q] = __shfl(acc[q], qb + 1);
            zg[q] = __shfl(acc[q], qb + 2);
            zo[q] = __shfl(acc[q], qb + 3);
        }
        ushort* Pout = planes + (size_t)((t + 1) & 1) * (3 * PLANE);
        #pragma unroll
        for (int q = 0; q < 4; ++q) {
            const size_t ridx = (size_t)(row0 + rbase + q) * HH + hid;
            float cold = (t > 0) ? cst[ridx] : 0.f;     // t==0: never read ws
            float ig = fsig(zi[q]), fg = fsig(zf[q]);
            float gv = ftanh(zg[q]), og = fsig(zo[q]);
            float cn = fg * cold + ig * gv;
            float hv = og * ftanh(cn);
            ushort c0 = bf16r(hv); float r1 = hv - bf16f(c0);
            ushort c1 = bf16r(r1); float r2 = r1 - bf16f(c1);
            ushort c2 = bf16r(r2);
            if (myp == 0)      Pout[ridx] = c0;
            else if (myp == 1) Pout[PLANE + ridx] = c1;
            else if (myp == 2) Pout[2 * PLANE + ridx] = c2;
            else               cst[ridx] = cn;
        }
    }
}

extern "C" void kernel_launch(void* const* d_in, const int* in_sizes, int n_in,
                              void* d_out, int out_size, void* d_ws, size_t ws_size,
                              hipStream_t stream) {
    const float* x   = (const float*)d_in[0];
    const float* Wi  = (const float*)d_in[1];
    const float* Wh  = (const float*)d_in[2];
    const float* b   = (const float*)d_in[3];
    const float* lns = (const float*)d_in[4];
    const float* lnb = (const float*)d_in[5];
    const float* Wd  = (const float*)d_in[6];
    const float* bd  = (const float*)d_in[7];
    float* out = (float*)d_out;

    // ws layout: whp 3 planes (6 MB) | h planes 2x3 (1.5 MB) | c state (0.5 MB)
    ushort* whp    = (ushort*)d_ws;
    ushort* planes = whp + (size_t)3 * WPL;
    float*  cst    = (float*)(planes + (size_t)2 * 3 * PLANE);

    size_t smem = (size_t)3 * 32 * HH * sizeof(short);   // 98304 B
    hipFuncSetAttribute((const void*)lstm_step,
                        hipFuncAttributeMaxDynamicSharedMemorySize, (int)smem);

    wprep_kernel<<<dim3(8), dim3(256), 0, stream>>>(Wh, whp);
    for (int t = 0; t <= TT; ++t)
        lstm_step<<<dim3(256), dim3(512), smem, stream>>>(x, Wi, b, lns, lnb,
                                                          Wd, bd, whp, planes,
                                                          cst, out, t);
}

// Round 6
// 7734.101 us; speedup vs baseline: 6.5281x; 1.3553x over previous
//
#include <hip/hip_runtime.h>

#define BB 256
#define TT 512
#define HH 512
#define G4 2048
#define NTHR 512
#define NWG 256
#define GROUPS 8
#define SLICES 32               // col-slices per group
#define RPG 32                  // rows per group
#define HTOT (BB*HH)            // packed-uint h elems per buffer

typedef __attribute__((ext_vector_type(8))) short short8;
typedef __attribute__((ext_vector_type(4))) float f32x4;

__device__ __forceinline__ ushort bf16r(float f) {          // RNE fp32->bf16
    unsigned u = __float_as_uint(f);
    return (ushort)((u + 0x7FFFu + ((u >> 16) & 1u)) >> 16);
}
__device__ __forceinline__ float bf16f(ushort s) {
    return __uint_as_float(((unsigned)s) << 16);
}
__device__ __forceinline__ float fsig(float x) {
    float e = exp2f(fminf(-1.44269504f * x, 80.f));
    return 1.f / (1.f + e);
}
__device__ __forceinline__ float ftanh(float x) {
    float e = exp2f(fminf(-2.88539008f * x, 80.f));
    return (1.f - e) / (1.f + e);
}

// ---- group barrier: agent-scope atomics only (round-2/3-proven), no fences.
// __syncthreads on entry drains each wave's vmcnt -> h stores are at MALL.
__device__ __forceinline__ void group_barrier(unsigned* bar, int g) {
    __syncthreads();
    if (threadIdx.x == 0) {
        unsigned* cnt = bar + g * 64;
        unsigned* gen = bar + (GROUPS + g) * 64;
        unsigned old = __hip_atomic_load(gen, __ATOMIC_RELAXED, __HIP_MEMORY_SCOPE_AGENT);
        unsigned a = __hip_atomic_fetch_add(cnt, 1u, __ATOMIC_RELAXED, __HIP_MEMORY_SCOPE_AGENT);
        if (a == SLICES - 1) {
            __hip_atomic_store(cnt, 0u, __ATOMIC_RELAXED, __HIP_MEMORY_SCOPE_AGENT);
            __hip_atomic_fetch_add(gen, 1u, __ATOMIC_RELAXED, __HIP_MEMORY_SCOPE_AGENT);
        } else {
            int spins = 0;
            while (__hip_atomic_load(gen, __ATOMIC_RELAXED, __HIP_MEMORY_SCOPE_AGENT) == old
                   && ++spins < (1 << 20))
                __builtin_amdgcn_s_sleep(2);
        }
    }
    __syncthreads();
}

__global__ __launch_bounds__(NTHR, 1)
void lstm_pers(const float* __restrict__ x, const float* __restrict__ Wi,
               const float* __restrict__ Wh, const float* __restrict__ bias,
               const float* __restrict__ lns, const float* __restrict__ lnb,
               const float* __restrict__ Wd, const float* __restrict__ bd,
               float* __restrict__ out, unsigned* __restrict__ hb,
               ushort* __restrict__ wmid, unsigned* __restrict__ bar)
{
    extern __shared__ char smem[];
    short* sHhi  = (short*)smem;                   // [32][512] swizzled   32 KB
    short* sHmid = (short*)(smem + 32768);         // [32][512] swizzled   32 KB
    short* sWhi  = (short*)(smem + 65536);         // [64 gc][512] swizzled 64 KB
    float* sWd   = (float*)(smem + 131072);        // [512*3]               6 KB
    float* sLns  = (float*)(smem + 137216);        // [512]                 2 KB
    float* sLnb  = (float*)(smem + 139264);        // [512]                 2 KB
    float* sWi   = (float*)(smem + 141312);        // [3][64]             768 B
    float* sBias = (float*)(smem + 142080);        // [64]                256 B

    const int bid = blockIdx.x, tid = threadIdx.x;
    const int g     = bid >> 5;          // row group 0..7
    const int slice = bid & 31;          // col slice 0..31
    const int grow0 = g * RPG;
    const int hid0  = slice * 16;

    // ---- prologue: decompose this wg's W slice (64 gc x 512 k) ----
    // hi plane -> LDS [col][k^swz]; mid plane -> private global, fragment-linear.
    for (int cc = tid; cc < 4096; cc += NTHR) {    // 8-elem chunks
        int cl = cc & 15, rest = cc >> 4;
        int kq = rest & 3, kc = (rest >> 2) & 15, tc = rest >> 6;
        int col = tc * 16 + cl;
        int k0 = kc * 32 + kq * 8;
        int gc = ((col & 3) << 9) + hid0 + (col >> 2);
        short8 vh, vm;
        #pragma unroll
        for (int j = 0; j < 8; ++j) {
            float w = Wh[(size_t)(k0 + j) * G4 + gc];
            ushort c0 = bf16r(w); float r1 = w - bf16f(c0);
            vh[j] = (short)c0; vm[j] = (short)bf16r(r1);
        }
        *(short8*)&sWhi[col * 512 + (k0 ^ ((col & 7) << 3))] = vh;
        *(short8*)&wmid[((size_t)bid * 4096 + cc) * 8] = vm;
    }
    if (tid < 64) {
        int gc = ((tid & 3) << 9) + hid0 + (tid >> 2);
        sBias[tid] = bias[gc];
        #pragma unroll
        for (int f = 0; f < 3; ++f) sWi[f * 64 + tid] = Wi[(size_t)f * G4 + gc];
    }
    for (int i = tid; i < 1536; i += NTHR) sWd[i] = Wd[i];
    for (int i = tid; i < 512; i += NTHR) { sLns[i] = lns[i]; sLnb[i] = lnb[i]; }
    __syncthreads();

    const int wave = tid >> 6, lane = tid & 63;
    const int rt = wave >> 2, tc = wave & 3;       // 2 row-tiles x 4 col-tiles
    const int cl = lane & 15, kq = lane >> 4;
    const int row_l = rt * 16 + cl;                // A row (local)
    const int aswz = (row_l & 7) << 3;
    const int col_l = tc * 16 + cl;                // gate-col (local)
    const int bswz = (col_l & 7) << 3;
    const int rbase = rt * 16 + kq * 4;            // C row base (local)
    const int qb = lane & ~3;
    const int hid = hid0 + tc * 4 + (cl >> 2);     // hidden col of this quad
    const int hswz = (slice & 7) << 3;             // head-row swizzle

    float creg[4] = {0.f, 0.f, 0.f, 0.f};

    for (int it = 0; it <= TT; ++it) {
        const unsigned* hin = hb + (size_t)(it & 1) * HTOT;
        unsigned*      hout = hb + (size_t)((it + 1) & 1) * HTOT;

        // ---- stage group's h(it-1): 32 rows x 512 k, packed hi|mid ----
        if (it > 0) {
            for (int i = tid; i < RPG * HH; i += NTHR) {
                int row = i >> 9, k = i & 511;
                unsigned v = __hip_atomic_load(&hin[(size_t)(grow0 + row) * HH + k],
                                               __ATOMIC_RELAXED, __HIP_MEMORY_SCOPE_AGENT);
                int ko = row * 512 + (k ^ ((row & 7) << 3));
                sHhi[ko]  = (short)(v & 0xffffu);
                sHmid[ko] = (short)(v >> 16);
            }
        }
        __syncthreads();

        // ---- output head for t = it-1 (row grow0+slice), wave 7 ----
        if (it >= 1 && wave == 7) {
            const int base = slice * 512 + ((lane * 8) ^ hswz);
            short8 vh = *(const short8*)&sHhi[base];
            short8 vm = *(const short8*)&sHmid[base];
            float h[8]; float s = 0.f, ss = 0.f;
            #pragma unroll
            for (int j = 0; j < 8; ++j) {
                h[j] = bf16f((ushort)vh[j]) + bf16f((ushort)vm[j]);
                s += h[j]; ss += h[j] * h[j];
            }
            #pragma unroll
            for (int d = 1; d < 64; d <<= 1) { s += __shfl_xor(s, d); ss += __shfl_xor(ss, d); }
            float mu = s * (1.f / 512.f);
            float rstd = rsqrtf(ss * (1.f / 512.f) - mu * mu + 1e-6f);
            float d0 = 0.f, d1 = 0.f, d2 = 0.f;
            #pragma unroll
            for (int j = 0; j < 8; ++j) {
                int col = lane * 8 + j;
                float y = (h[j] - mu) * rstd * sLns[col] + sLnb[col];
                y = fmaxf(y, 0.f);
                d0 = fmaf(y, sWd[col * 3 + 0], d0);
                d1 = fmaf(y, sWd[col * 3 + 1], d1);
                d2 = fmaf(y, sWd[col * 3 + 2], d2);
            }
            #pragma unroll
            for (int d = 1; d < 64; d <<= 1) {
                d0 += __shfl_xor(d0, d); d1 += __shfl_xor(d1, d); d2 += __shfl_xor(d2, d);
            }
            if (lane == 0) {
                size_t o = ((size_t)(grow0 + slice) * TT + (it - 1)) * 3;
                out[o + 0] = d0 + bd[0];
                out[o + 1] = d1 + bd[1];
                out[o + 2] = d2 + bd[2];
            }
        }

        if (it < TT) {
            // xg = x@Wi + b (fp32 exact)
            f32x4 acc;
            {
                float b0 = sBias[col_l], w0 = sWi[col_l];
                float w1 = sWi[64 + col_l], w2 = sWi[128 + col_l];
                #pragma unroll
                for (int q = 0; q < 4; ++q) {
                    const float* xp = x + ((size_t)(grow0 + rbase + q) * TT + it) * 3;
                    acc[q] = b0 + xp[0] * w0 + xp[1] * w1 + xp[2] * w2;
                }
            }
            // h @ Wh : 3-pass split-bf16 MFMA over K=512
            if (it > 0) {
                const short8* wmBase = (const short8*)(wmid + (size_t)bid * 4096 * 8);
                #pragma unroll 4
                for (int kc = 0; kc < 16; ++kc) {
                    int k0 = kc * 32 + kq * 8;
                    short8 Ah = *(const short8*)&sHhi[row_l * 512 + (k0 ^ aswz)];
                    short8 Am = *(const short8*)&sHmid[row_l * 512 + (k0 ^ aswz)];
                    short8 Bh = *(const short8*)&sWhi[col_l * 512 + (k0 ^ bswz)];
                    short8 Bm = wmBase[(tc * 64 + kc * 4 + kq) * 16 + cl];
                    acc = __builtin_amdgcn_mfma_f32_16x16x32_bf16(Ah, Bh, acc, 0, 0, 0);
                    acc = __builtin_amdgcn_mfma_f32_16x16x32_bf16(Ah, Bm, acc, 0, 0, 0);
                    acc = __builtin_amdgcn_mfma_f32_16x16x32_bf16(Am, Bh, acc, 0, 0, 0);
                }
            }
            // gather gates across quad; update c; pack h hi|mid
            float zi[4], zf[4], zg[4], zo[4];
            #pragma unroll
            for (int q = 0; q < 4; ++q) {
                zi[q] = __shfl(acc[q], qb + 0);
                zf[q] = __shfl(acc[q], qb + 1);
                zg[q] = __shfl(acc[q], qb + 2);
                zo[q] = __shfl(acc[q], qb + 3);
            }
            unsigned mypack = 0;
            const int qsel = lane & 3;
            #pragma unroll
            for (int q = 0; q < 4; ++q) {
                float ig = fsig(zi[q]), fg = fsig(zf[q]);
                float gv = ftanh(zg[q]), og = fsig(zo[q]);
                creg[q] = fg * creg[q] + ig * gv;
                float hv = og * ftanh(creg[q]);
                ushort c0 = bf16r(hv);
                ushort c1 = bf16r(hv - bf16f(c0));
                if (q == qsel) mypack = (unsigned)c0 | ((unsigned)c1 << 16);
            }
            __hip_atomic_store(&hout[(size_t)(grow0 + rbase + qsel) * HH + hid], mypack,
                               __ATOMIC_RELAXED, __HIP_MEMORY_SCOPE_AGENT);
            group_barrier(bar, g);
        }
    }
}

extern "C" void kernel_launch(void* const* d_in, const int* in_sizes, int n_in,
                              void* d_out, int out_size, void* d_ws, size_t ws_size,
                              hipStream_t stream) {
    const float* x   = (const float*)d_in[0];
    const float* Wi  = (const float*)d_in[1];
    const float* Wh  = (const float*)d_in[2];
    const float* b   = (const float*)d_in[3];
    const float* lns = (const float*)d_in[4];
    const float* lnb = (const float*)d_in[5];
    const float* Wd  = (const float*)d_in[6];
    const float* bd  = (const float*)d_in[7];
    float* out = (float*)d_out;

    // ws: h packed 2 x 256x512 uint (2 MB) | wmid 256wg x 32K ushort (16 MB) | bar
    unsigned* hb   = (unsigned*)d_ws;
    ushort*   wmid = (ushort*)((char*)d_ws + (size_t)2 * HTOT * 4);
    unsigned* bar  = (unsigned*)((char*)d_ws + (size_t)2 * HTOT * 4
                                 + (size_t)NWG * 4096 * 8 * 2);

    hipMemsetAsync(bar, 0, 2 * GROUPS * 64 * sizeof(unsigned), stream);

    size_t smem = 142336;
    hipFuncSetAttribute((const void*)lstm_pers,
                        hipFuncAttributeMaxDynamicSharedMemorySize, (int)smem);

    void* args[] = { (void*)&x, (void*)&Wi, (void*)&Wh, (void*)&b, (void*)&lns,
                     (void*)&lnb, (void*)&Wd, (void*)&bd, (void*)&out,
                     (void*)&hb, (void*)&wmid, (void*)&bar };
    hipLaunchCooperativeKernel((void*)lstm_pers, dim3(NWG), dim3(NTHR),
                               args, (unsigned int)smem, stream);
}

// Round 7
// 5643.282 us; speedup vs baseline: 8.9467x; 1.3705x over previous
//
#include <hip/hip_runtime.h>

#define BB 256
#define TT 512
#define HH 512
#define G4 2048
#define NTHR 512
#define NWG 256
#define GROUPS 8
#define SLICES 32
#define RPG 32
#define HTOT (BB*HH)

typedef __attribute__((ext_vector_type(8))) short short8;
typedef __attribute__((ext_vector_type(4))) float f32x4;
typedef __attribute__((ext_vector_type(4))) unsigned uint4v;

__device__ __forceinline__ ushort bf16r(float f) {          // RNE fp32->bf16
    unsigned u = __float_as_uint(f);
    return (ushort)((u + 0x7FFFu + ((u >> 16) & 1u)) >> 16);
}
__device__ __forceinline__ float bf16f(ushort s) {
    return __uint_as_float(((unsigned)s) << 16);
}
__device__ __forceinline__ float fsig(float x) {
    float e = exp2f(fminf(-1.44269504f * x, 80.f));
    return 1.f / (1.f + e);
}
__device__ __forceinline__ float ftanh(float x) {
    float e = exp2f(fminf(-2.88539008f * x, 80.f));
    return (1.f - e) / (1.f + e);
}

// coherent 16B load (MALL-visible, bypasses stale L2 lines)
#define LDA16(dst, p) asm volatile("global_load_dwordx4 %0, %1, off sc0 sc1" \
                                   : "=v"(dst) : "v"(p))
#define WAITV(n) do { asm volatile("s_waitcnt vmcnt(" #n ")" ::: "memory"); \
                      __builtin_amdgcn_sched_barrier(0); } while (0)

__global__ __launch_bounds__(NTHR, 1)
void lstm_v7(const float* __restrict__ x, const float* __restrict__ Wi,
             const float* __restrict__ Wh, const float* __restrict__ bias,
             const float* __restrict__ lns, const float* __restrict__ lnb,
             const float* __restrict__ Wd, const float* __restrict__ bd,
             float* __restrict__ out, unsigned* __restrict__ hb,
             unsigned* __restrict__ flags)
{
    extern __shared__ char smem[];
    short* sWhi  = (short*)smem;                   // [64][512] swizzled  64 KB
    short* sWmid = (short*)(smem + 65536);         // [64][512] swizzled  64 KB
    float* sWd   = (float*)(smem + 131072);        // [512*3]
    float* sLns  = (float*)(smem + 137216);
    float* sLnb  = (float*)(smem + 139264);
    float* sWi   = (float*)(smem + 141312);        // [3][64]
    float* sBias = (float*)(smem + 142080);        // [64]
    float* sRed  = (float*)(smem + 142336);        // 48 floats

    const int bid = blockIdx.x, tid = threadIdx.x;
    const int g = bid >> 5, slice = bid & 31;
    const int grow0 = g * RPG, hid0 = slice * 16;

    // ---- prologue: decompose W slice (64 gc x 512 k) into 2 LDS planes ----
    for (int cc = tid; cc < 4096; cc += NTHR) {
        int col = cc & 63, k0 = (cc >> 6) << 3;
        int gc = ((col & 3) << 9) + hid0 + (col >> 2);   // gate*512 + hid
        short8 vh, vm;
        #pragma unroll
        for (int j = 0; j < 8; ++j) {
            float w = Wh[(size_t)(k0 + j) * G4 + gc];
            ushort c0 = bf16r(w);
            vh[j] = (short)c0; vm[j] = (short)bf16r(w - bf16f(c0));
        }
        int base = col * 512 + (k0 ^ ((col & 7) << 3));
        *(short8*)&sWhi[base]  = vh;
        *(short8*)&sWmid[base] = vm;
    }
    if (tid < 64) {
        int gc = ((tid & 3) << 9) + hid0 + (tid >> 2);
        sBias[tid] = bias[gc];
        #pragma unroll
        for (int f = 0; f < 3; ++f) sWi[f * 64 + tid] = Wi[(size_t)f * G4 + gc];
    }
    for (int i = tid; i < 1536; i += NTHR) sWd[i] = Wd[i];
    for (int i = tid; i < 512; i += NTHR) { sLns[i] = lns[i]; sLnb[i] = lnb[i]; }
    __syncthreads();

    const int wave = tid >> 6, lane = tid & 63;
    const int rt = wave >> 2, tcw = wave & 3;      // 2 row-tiles x 4 col-tiles
    const int cl = lane & 15, kq = lane >> 4;
    const int col_l = tcw * 16 + cl;
    const int bswz = (col_l & 7) << 3;
    const int rbase = rt * 16 + kq * 4;
    const int qb = lane & ~3, qsel = lane & 3;
    const int hid = hid0 + tcw * 4 + (cl >> 2);
    const int arow = grow0 + rt * 16 + cl;

    float creg[4] = {0.f, 0.f, 0.f, 0.f};

    for (int it = 0; it <= TT; ++it) {
        const unsigned* hin = hb + (size_t)(it & 1) * HTOT;
        unsigned*      hout = hb + (size_t)((it + 1) & 1) * HTOT;

        // ---- distributed output head for t = it-1 (row grow0+slice) ----
        if (it >= 1) {
            const int hrow = grow0 + slice;
            unsigned v = __hip_atomic_load(&hin[(size_t)hrow * HH + tid],
                                           __ATOMIC_RELAXED, __HIP_MEMORY_SCOPE_AGENT);
            float hv = bf16f((ushort)(v & 0xffffu)) + bf16f((ushort)(v >> 16));
            float s = hv, sq = hv * hv;
            #pragma unroll
            for (int d = 1; d < 64; d <<= 1) { s += __shfl_xor(s, d); sq += __shfl_xor(sq, d); }
            if (lane == 0) { sRed[wave] = s; sRed[8 + wave] = sq; }
            __syncthreads();
            float S = 0.f, Q = 0.f;
            #pragma unroll
            for (int w = 0; w < 8; ++w) { S += sRed[w]; Q += sRed[8 + w]; }
            float mu = S * (1.f / 512.f);
            float rstd = rsqrtf(Q * (1.f / 512.f) - mu * mu + 1e-6f);
            float y = (hv - mu) * rstd * sLns[tid] + sLnb[tid];
            y = fmaxf(y, 0.f);
            float d0 = y * sWd[tid * 3 + 0];
            float d1 = y * sWd[tid * 3 + 1];
            float d2 = y * sWd[tid * 3 + 2];
            #pragma unroll
            for (int d = 1; d < 64; d <<= 1) {
                d0 += __shfl_xor(d0, d); d1 += __shfl_xor(d1, d); d2 += __shfl_xor(d2, d);
            }
            if (lane == 0) {
                sRed[16 + wave * 4 + 0] = d0;
                sRed[16 + wave * 4 + 1] = d1;
                sRed[16 + wave * 4 + 2] = d2;
            }
            __syncthreads();
            if (tid == 0) {
                float o0 = bd[0], o1 = bd[1], o2 = bd[2];
                #pragma unroll
                for (int w = 0; w < 8; ++w) {
                    o0 += sRed[16 + w * 4 + 0];
                    o1 += sRed[16 + w * 4 + 1];
                    o2 += sRed[16 + w * 4 + 2];
                }
                size_t o = ((size_t)hrow * TT + (it - 1)) * 3;
                out[o + 0] = o0; out[o + 1] = o1; out[o + 2] = o2;
            }
        }

        if (it < TT) {
            // xg = x@Wi + b (fp32 exact)
            f32x4 acc;
            {
                float b0 = sBias[col_l], w0 = sWi[col_l];
                float w1 = sWi[64 + col_l], w2 = sWi[128 + col_l];
                #pragma unroll
                for (int q = 0; q < 4; ++q) {
                    const float* xp = x + ((size_t)(grow0 + rbase + q) * TT + it) * 3;
                    acc[q] = b0 + xp[0] * w0 + xp[1] * w1 + xp[2] * w2;
                }
            }
            // h @ Wh: 3-pass split-bf16 MFMA, A direct from MALL, 4-deep pipeline
            if (it > 0) {
                const unsigned* ap = hin + (size_t)arow * HH + kq * 8;
                uint4v ab[32];
                LDA16(ab[0], ap +  0); LDA16(ab[1], ap +  4);
                LDA16(ab[2], ap + 32); LDA16(ab[3], ap + 36);
                LDA16(ab[4], ap + 64); LDA16(ab[5], ap + 68);
                LDA16(ab[6], ap + 96); LDA16(ab[7], ap + 100);
                #pragma unroll
                for (int kc = 0; kc < 16; ++kc) {
                    if (kc + 4 < 16) {
                        LDA16(ab[(kc + 4) * 2],     ap + (kc + 4) * 32);
                        LDA16(ab[(kc + 4) * 2 + 1], ap + (kc + 4) * 32 + 4);
                    }
                    if (kc < 12)      WAITV(8);
                    else if (kc == 12) WAITV(6);
                    else if (kc == 13) WAITV(4);
                    else if (kc == 14) WAITV(2);
                    else               WAITV(0);
                    uint4v a0 = ab[kc * 2], a1 = ab[kc * 2 + 1];
                    short8 Ah, Am;
                    #pragma unroll
                    for (int j = 0; j < 4; ++j) {
                        Ah[j]     = (short)(a0[j] & 0xffffu);
                        Am[j]     = (short)(a0[j] >> 16);
                        Ah[4 + j] = (short)(a1[j] & 0xffffu);
                        Am[4 + j] = (short)(a1[j] >> 16);
                    }
                    int k0 = kc * 32 + kq * 8;
                    int bo = col_l * 512 + (k0 ^ bswz);
                    short8 Bh = *(const short8*)&sWhi[bo];
                    short8 Bm = *(const short8*)&sWmid[bo];
                    acc = __builtin_amdgcn_mfma_f32_16x16x32_bf16(Ah, Bh, acc, 0, 0, 0);
                    acc = __builtin_amdgcn_mfma_f32_16x16x32_bf16(Ah, Bm, acc, 0, 0, 0);
                    acc = __builtin_amdgcn_mfma_f32_16x16x32_bf16(Am, Bh, acc, 0, 0, 0);
                }
            }
            // gather gates across the lane quad; update c; pack h hi|mid
            float zi[4], zf[4], zg[4], zo[4];
            #pragma unroll
            for (int q = 0; q < 4; ++q) {
                zi[q] = __shfl(acc[q], qb + 0);
                zf[q] = __shfl(acc[q], qb + 1);
                zg[q] = __shfl(acc[q], qb + 2);
                zo[q] = __shfl(acc[q], qb + 3);
            }
            unsigned mypack = 0;
            #pragma unroll
            for (int q = 0; q < 4; ++q) {
                float ig = fsig(zi[q]), fg = fsig(zf[q]);
                float gv = ftanh(zg[q]), og = fsig(zo[q]);
                creg[q] = fg * creg[q] + ig * gv;
                float hv = og * ftanh(creg[q]);
                ushort c0 = bf16r(hv);
                ushort c1 = bf16r(hv - bf16f(c0));
                if (q == qsel) mypack = (unsigned)c0 | ((unsigned)c1 << 16);
            }
            __hip_atomic_store(&hout[(size_t)(grow0 + rbase + qsel) * HH + hid], mypack,
                               __ATOMIC_RELAXED, __HIP_MEMORY_SCOPE_AGENT);

            // ---- flag barrier: store own step count, poll 32 flags ----
            __syncthreads();                        // all h stores drained
            if (tid == 0)
                __hip_atomic_store(&flags[g * SLICES + slice], (unsigned)(it + 1),
                                   __ATOMIC_RELAXED, __HIP_MEMORY_SCOPE_AGENT);
            if (wave == 0) {
                const unsigned tgt = (unsigned)(it + 1);
                int spins = 0;
                while (true) {
                    unsigned v = (lane < SLICES)
                        ? __hip_atomic_load(&flags[g * SLICES + lane],
                                            __ATOMIC_RELAXED, __HIP_MEMORY_SCOPE_AGENT)
                        : tgt;
                    if (__all(v >= tgt)) break;
                    if (++spins > (1 << 22)) break;
                    __builtin_amdgcn_s_sleep(1);
                }
            }
            __syncthreads();
        }
    }
}

extern "C" void kernel_launch(void* const* d_in, const int* in_sizes, int n_in,
                              void* d_out, int out_size, void* d_ws, size_t ws_size,
                              hipStream_t stream) {
    const float* x   = (const float*)d_in[0];
    const float* Wi  = (const float*)d_in[1];
    const float* Wh  = (const float*)d_in[2];
    const float* b   = (const float*)d_in[3];
    const float* lns = (const float*)d_in[4];
    const float* lnb = (const float*)d_in[5];
    const float* Wd  = (const float*)d_in[6];
    const float* bd  = (const float*)d_in[7];
    float* out = (float*)d_out;

    unsigned* hb    = (unsigned*)d_ws;                              // 2 x 256x512 uint = 1 MB
    unsigned* flags = (unsigned*)((char*)d_ws + (size_t)2 * HTOT * 4);

    hipMemsetAsync(flags, 0, GROUPS * SLICES * sizeof(unsigned), stream);

    size_t smem = 142528;
    hipFuncSetAttribute((const void*)lstm_v7,
                        hipFuncAttributeMaxDynamicSharedMemorySize, (int)smem);

    void* args[] = { (void*)&x, (void*)&Wi, (void*)&Wh, (void*)&b, (void*)&lns,
                     (void*)&lnb, (void*)&Wd, (void*)&bd, (void*)&out,
                     (void*)&hb, (void*)&flags };
    hipLaunchCooperativeKernel((void*)lstm_v7, dim3(NWG), dim3(NTHR),
                               args, (unsigned int)smem, stream);
}

// Round 8
// 4767.268 us; speedup vs baseline: 10.5907x; 1.1838x over previous
//
#include <hip/hip_runtime.h>

#define BB 256
#define TT 512
#define HH 512
#define G4 2048
#define NTHR 512
#define NWG 256
#define GROUPS 8
#define SLICES 32
#define HTOT (BB*HH)

// bar word layout
#define FLAGW(g,s) ((g)*64 + (s))
#define DCNT     (8*64)
#define DGEN     (8*64 + 16)
#define XCCOF(g) (8*64 + 32 + (g))
#define BADF(g)  (8*64 + 48 + (g))

typedef __attribute__((ext_vector_type(8))) short short8;
typedef __attribute__((ext_vector_type(4))) float f32x4;

__device__ __forceinline__ ushort bf16r(float f) {          // RNE fp32->bf16
    unsigned u = __float_as_uint(f);
    return (ushort)((u + 0x7FFFu + ((u >> 16) & 1u)) >> 16);
}
__device__ __forceinline__ float bf16f(ushort s) {
    return __uint_as_float(((unsigned)s) << 16);
}
__device__ __forceinline__ float fsig(float x) {
    float e = exp2f(fminf(-1.44269504f * x, 80.f));
    return 1.f / (1.f + e);
}
__device__ __forceinline__ float ftanh(float x) {
    float e = exp2f(fminf(-2.88539008f * x, 80.f));
    return (1.f - e) / (1.f + e);
}

#define WAITV(n) do { asm volatile("s_waitcnt vmcnt(" #n ")" ::: "memory"); \
                      __builtin_amdgcn_sched_barrier(0); } while (0)

// SC1=true: MALL-coherent (cross-XCD safe). SC1=false: XCD-L2 local (FAST).
template<bool SC1>
__device__ __forceinline__ void lda16(short8* d, const ushort* p) {
    if constexpr (SC1)
        asm volatile("global_load_dwordx4 %0, %1, off sc0 sc1" : "=v"(*d) : "v"(p));
    else
        asm volatile("global_load_dwordx4 %0, %1, off sc0" : "=v"(*d) : "v"(p));
}
template<bool SC1>
__device__ __forceinline__ void ldu16(unsigned* d, const ushort* p) {
    if constexpr (SC1)
        asm volatile("global_load_ushort %0, %1, off sc0 sc1" : "=v"(*d) : "v"(p));
    else
        asm volatile("global_load_ushort %0, %1, off sc0" : "=v"(*d) : "v"(p));
}
template<bool SC1>
__device__ __forceinline__ void sts2(ushort* p, unsigned v) {
    if constexpr (SC1)
        asm volatile("global_store_short %0, %1, off sc0 sc1" :: "v"(p), "v"(v) : "memory");
    else
        asm volatile("global_store_short %0, %1, off" :: "v"(p), "v"(v) : "memory");
}

__device__ void dev_barrier(unsigned* bar) {
    __syncthreads();
    if (threadIdx.x == 0) {
        unsigned old = __hip_atomic_load(bar + DGEN, __ATOMIC_RELAXED, __HIP_MEMORY_SCOPE_AGENT);
        unsigned a = __hip_atomic_fetch_add(bar + DCNT, 1u, __ATOMIC_RELAXED, __HIP_MEMORY_SCOPE_AGENT);
        if (a == NWG - 1) {
            __hip_atomic_store(bar + DCNT, 0u, __ATOMIC_RELAXED, __HIP_MEMORY_SCOPE_AGENT);
            __hip_atomic_fetch_add(bar + DGEN, 1u, __ATOMIC_RELAXED, __HIP_MEMORY_SCOPE_AGENT);
        } else {
            int sp = 0;
            while (__hip_atomic_load(bar + DGEN, __ATOMIC_RELAXED, __HIP_MEMORY_SCOPE_AGENT) == old
                   && ++sp < (1 << 20))
                __builtin_amdgcn_s_sleep(2);
        }
    }
    __syncthreads();
}

template<bool FAST>
__device__ void run_steps(const float* __restrict__ x, const float* __restrict__ lns,
                          const float* __restrict__ lnb, const float* __restrict__ Wd,
                          const float* __restrict__ bd, float* __restrict__ out,
                          ushort* __restrict__ hbHi, ushort* __restrict__ hbMid,
                          unsigned* __restrict__ bar, short* sWhi, short* sWmid,
                          float* zsum, float* sWi, float* sBias, float* sRed,
                          int g, int slice)
{
    const int tid = threadIdx.x;
    const int wave = tid >> 6, lane = tid & 63;
    const int ks = wave & 1, gp = (wave >> 1) & 1, rt = (wave >> 2) & 1;
    const int cl = lane & 15, kq4 = (lane >> 4) << 2, kq8 = (lane >> 4) << 3;
    const int qb = lane & ~3, qsel = lane & 3;
    const int grow0 = g * 32, hid0 = slice * 16;
    const int rbase = rt * 16 + kq4;
    const int arow = grow0 + rt * 16 + cl;
    const int bswz = (cl & 7) << 3;
    const int cA = gp * 32 + cl, cB = cA + 16;

    float creg[2][4] = {{0.f,0.f,0.f,0.f},{0.f,0.f,0.f,0.f}};

    for (int it = 0; it <= TT; ++it) {
        const ushort* hiIn = hbHi + (size_t)(it & 1) * HTOT;
        const ushort* mdIn = hbMid + (size_t)(it & 1) * HTOT;
        ushort* hiOut = hbHi + (size_t)((it + 1) & 1) * HTOT;
        ushort* mdOut = hbMid + (size_t)((it + 1) & 1) * HTOT;

        if (it < TT) {
            f32x4 acc0 = {0.f,0.f,0.f,0.f}, acc1 = {0.f,0.f,0.f,0.f};
            if (ks == 0) {   // xg + bias added exactly once (on K-half 0)
                float b0 = sBias[cA], b1 = sBias[cB];
                float wa0 = sWi[cA], wb0 = sWi[64+cA], wc0 = sWi[128+cA];
                float wa1 = sWi[cB], wb1 = sWi[64+cB], wc1 = sWi[128+cB];
                #pragma unroll
                for (int q = 0; q < 4; ++q) {
                    const float* xp = x + ((size_t)(grow0 + rbase + q) * TT + it) * 3;
                    float x0 = xp[0], x1 = xp[1], x2 = xp[2];
                    acc0[q] = b0 + x0*wa0 + x1*wb0 + x2*wc0;
                    acc1[q] = b1 + x0*wa1 + x1*wb1 + x2*wc1;
                }
            }
            if (it > 0) {
                const ushort* aHi = hiIn + (size_t)arow * HH + ks*256 + kq8;
                const ushort* aMd = mdIn + (size_t)arow * HH + ks*256 + kq8;
                short8 A[16];
                WAITV(0);                       // clean FIFO -> exact counts
                #pragma unroll
                for (int kc = 0; kc < 8; ++kc) {
                    lda16<!FAST>(&A[kc*2],   aHi + kc*32);
                    lda16<!FAST>(&A[kc*2+1], aMd + kc*32);
                }
                #pragma unroll
                for (int kc = 0; kc < 8; ++kc) {
                    if      (kc == 0) WAITV(14);
                    else if (kc == 1) WAITV(12);
                    else if (kc == 2) WAITV(10);
                    else if (kc == 3) WAITV(8);
                    else if (kc == 4) WAITV(6);
                    else if (kc == 5) WAITV(4);
                    else if (kc == 6) WAITV(2);
                    else              WAITV(0);
                    int k0 = ks*256 + kc*32 + kq8;
                    int boA = cA*512 + (k0 ^ bswz);
                    int boB = cB*512 + (k0 ^ bswz);
                    short8 Ah = A[kc*2], Am = A[kc*2+1];
                    short8 BhA = *(const short8*)&sWhi[boA];
                    short8 BmA = *(const short8*)&sWmid[boA];
                    short8 BhB = *(const short8*)&sWhi[boB];
                    short8 BmB = *(const short8*)&sWmid[boB];
                    acc0 = __builtin_amdgcn_mfma_f32_16x16x32_bf16(Ah, BhA, acc0, 0,0,0);
                    acc1 = __builtin_amdgcn_mfma_f32_16x16x32_bf16(Ah, BhB, acc1, 0,0,0);
                    acc0 = __builtin_amdgcn_mfma_f32_16x16x32_bf16(Ah, BmA, acc0, 0,0,0);
                    acc1 = __builtin_amdgcn_mfma_f32_16x16x32_bf16(Ah, BmB, acc1, 0,0,0);
                    acc0 = __builtin_amdgcn_mfma_f32_16x16x32_bf16(Am, BhA, acc0, 0,0,0);
                    acc1 = __builtin_amdgcn_mfma_f32_16x16x32_bf16(Am, BhB, acc1, 0,0,0);
                }
            }
            // ---- K-split combine through LDS ----
            if (ks == 1) {
                #pragma unroll
                for (int q = 0; q < 4; ++q) {
                    zsum[(rbase + q)*64 + cA] = acc0[q];
                    zsum[(rbase + q)*64 + cB] = acc1[q];
                }
            }
            __syncthreads();
            if (ks == 0) {
                #pragma unroll
                for (int q = 0; q < 4; ++q) {
                    acc0[q] += zsum[(rbase + q)*64 + cA];
                    acc1[q] += zsum[(rbase + q)*64 + cB];
                }
                #pragma unroll
                for (int gt = 0; gt < 2; ++gt) {
                    float zi[4], zf[4], zg[4], zo[4];
                    #pragma unroll
                    for (int q = 0; q < 4; ++q) {
                        float a = gt ? acc1[q] : acc0[q];
                        zi[q] = __shfl(a, qb + 0);
                        zf[q] = __shfl(a, qb + 1);
                        zg[q] = __shfl(a, qb + 2);
                        zo[q] = __shfl(a, qb + 3);
                    }
                    int hid = hid0 + gp*8 + gt*4 + (cl >> 2);
                    size_t ridx = (size_t)(grow0 + rbase + qsel) * HH + hid;
                    #pragma unroll
                    for (int q = 0; q < 4; ++q) {
                        float ig = fsig(zi[q]), fg = fsig(zf[q]);
                        float gv = ftanh(zg[q]), og = fsig(zo[q]);
                        creg[gt][q] = fg * creg[gt][q] + ig * gv;
                        float hv = og * ftanh(creg[gt][q]);
                        if (q == qsel) {
                            ushort h0 = bf16r(hv);
                            ushort h1 = bf16r(hv - bf16f(h0));
                            sts2<!FAST>(hiOut + ridx, (unsigned)h0);
                            sts2<!FAST>(mdOut + ridx, (unsigned)h1);
                        }
                    }
                }
            }
            __syncthreads();                  // drains h stores (vmcnt0)
            if (tid == 0)
                __hip_atomic_store(&bar[FLAGW(g, slice)], (unsigned)(it + 1),
                                   __ATOMIC_RELAXED, __HIP_MEMORY_SCOPE_AGENT);
        }

        // ---- output head for t = it-1: overlapped with peers' step progress ----
        if (it >= 1) {
            const int row_h = grow0 + slice;
            unsigned vh_, vm_;
            ldu16<!FAST>(&vh_, hiIn + (size_t)row_h * HH + tid);
            ldu16<!FAST>(&vm_, mdIn + (size_t)row_h * HH + tid);
            WAITV(0);
            float hv = bf16f((ushort)vh_) + bf16f((ushort)vm_);
            float s = hv, sq = hv * hv;
            #pragma unroll
            for (int d = 1; d < 64; d <<= 1) { s += __shfl_xor(s, d); sq += __shfl_xor(sq, d); }
            if (lane == 0) { sRed[wave] = s; sRed[8 + wave] = sq; }
            __syncthreads();
            float S = 0.f, Q = 0.f;
            #pragma unroll
            for (int w = 0; w < 8; ++w) { S += sRed[w]; Q += sRed[8 + w]; }
            float mu = S * (1.f / 512.f);
            float rstd = rsqrtf(Q * (1.f / 512.f) - mu * mu + 1e-6f);
            float y = (hv - mu) * rstd * lns[tid] + lnb[tid];
            y = fmaxf(y, 0.f);
            float d0 = y * Wd[tid*3+0], d1 = y * Wd[tid*3+1], d2 = y * Wd[tid*3+2];
            #pragma unroll
            for (int d = 1; d < 64; d <<= 1) {
                d0 += __shfl_xor(d0, d); d1 += __shfl_xor(d1, d); d2 += __shfl_xor(d2, d);
            }
            if (lane == 0) {
                sRed[16 + wave*4 + 0] = d0;
                sRed[16 + wave*4 + 1] = d1;
                sRed[16 + wave*4 + 2] = d2;
            }
            __syncthreads();
            if (tid == 0) {
                float o0 = bd[0], o1 = bd[1], o2 = bd[2];
                #pragma unroll
                for (int w = 0; w < 8; ++w) {
                    o0 += sRed[16 + w*4 + 0];
                    o1 += sRed[16 + w*4 + 1];
                    o2 += sRed[16 + w*4 + 2];
                }
                size_t o = ((size_t)row_h * TT + (it - 1)) * 3;
                out[o + 0] = o0; out[o + 1] = o1; out[o + 2] = o2;
            }
        }

        if (it < TT) {   // poll group flags (bounded spin -> no hang mode)
            if (wave == 0) {
                const unsigned tgt = (unsigned)(it + 1);
                int spins = 0;
                while (true) {
                    unsigned v = (lane < SLICES)
                        ? __hip_atomic_load(&bar[FLAGW(g, lane)], __ATOMIC_RELAXED,
                                            __HIP_MEMORY_SCOPE_AGENT)
                        : tgt;
                    if (__all(v >= tgt)) break;
                    if (++spins > (1 << 18)) break;
                    __builtin_amdgcn_s_sleep(1);
                }
            }
            __syncthreads();
        }
    }
}

__global__ __launch_bounds__(NTHR, 1)
void lstm_v8(const float* __restrict__ x, const float* __restrict__ Wi,
             const float* __restrict__ Wh, const float* __restrict__ bias,
             const float* __restrict__ lns, const float* __restrict__ lnb,
             const float* __restrict__ Wd, const float* __restrict__ bd,
             float* __restrict__ out, ushort* __restrict__ hbHi,
             ushort* __restrict__ hbMid, unsigned* __restrict__ bar)
{
    extern __shared__ char smem[];
    short* sWhi  = (short*)smem;                    // [64][512] swizzled  64 KB
    short* sWmid = (short*)(smem + 65536);          // [64][512] swizzled  64 KB
    float* zsum  = (float*)(smem + 131072);         // [32][64] f32         8 KB
    float* sWi   = (float*)(smem + 139264);         // [3][64]
    float* sBias = (float*)(smem + 140032);         // [64]
    float* sRed  = (float*)(smem + 140288);         // 48 f32
    unsigned* sFlag = (unsigned*)(smem + 140544);

    const int bid = blockIdx.x, tid = threadIdx.x;
    const int g = bid & 7, slice = bid >> 3;        // group = XCD under round-robin
    const int hid0 = slice * 16;

    // ---- prologue: decompose W slice (64 gc x 512 k) into 2 LDS planes ----
    for (int cc = tid; cc < 4096; cc += NTHR) {
        int col = cc & 63, k0 = (cc >> 6) << 3;
        int gc = ((col & 3) << 9) + hid0 + (col >> 2);   // gate*512 + hid
        short8 vh, vm;
        #pragma unroll
        for (int j = 0; j < 8; ++j) {
            float w = Wh[(size_t)(k0 + j) * G4 + gc];
            ushort c0 = bf16r(w);
            vh[j] = (short)c0; vm[j] = (short)bf16r(w - bf16f(c0));
        }
        int base = col * 512 + (k0 ^ ((col & 7) << 3));
        *(short8*)&sWhi[base]  = vh;
        *(short8*)&sWmid[base] = vm;
    }
    if (tid < 64) {
        int gc = ((tid & 3) << 9) + hid0 + (tid >> 2);
        sBias[tid] = bias[gc];
        #pragma unroll
        for (int f = 0; f < 3; ++f) sWi[f * 64 + tid] = Wi[(size_t)f * G4 + gc];
    }

    // ---- placement detection: is group g XCD-uniform? ----
    unsigned xcc;
    asm volatile("s_getreg_b32 %0, hwreg(HW_REG_XCC_ID)" : "=s"(xcc));
    if (tid == 0 && slice == 0)
        __hip_atomic_store(&bar[XCCOF(g)], xcc, __ATOMIC_RELAXED, __HIP_MEMORY_SCOPE_AGENT);
    dev_barrier(bar);
    if (tid == 0) {
        unsigned lx = __hip_atomic_load(&bar[XCCOF(g)], __ATOMIC_RELAXED,
                                        __HIP_MEMORY_SCOPE_AGENT);
        if (lx != xcc)
            __hip_atomic_fetch_or(&bar[BADF(g)], 1u, __ATOMIC_RELAXED,
                                  __HIP_MEMORY_SCOPE_AGENT);
    }
    dev_barrier(bar);
    if (tid == 0)
        sFlag[0] = (__hip_atomic_load(&bar[BADF(g)], __ATOMIC_RELAXED,
                                      __HIP_MEMORY_SCOPE_AGENT) == 0u) ? 1u : 0u;
    __syncthreads();

    if (sFlag[0])
        run_steps<true >(x, lns, lnb, Wd, bd, out, hbHi, hbMid, bar,
                         sWhi, sWmid, zsum, sWi, sBias, sRed, g, slice);
    else
        run_steps<false>(x, lns, lnb, Wd, bd, out, hbHi, hbMid, bar,
                         sWhi, sWmid, zsum, sWi, sBias, sRed, g, slice);
}

extern "C" void kernel_launch(void* const* d_in, const int* in_sizes, int n_in,
                              void* d_out, int out_size, void* d_ws, size_t ws_size,
                              hipStream_t stream) {
    const float* x   = (const float*)d_in[0];
    const float* Wi  = (const float*)d_in[1];
    const float* Wh  = (const float*)d_in[2];
    const float* b   = (const float*)d_in[3];
    const float* lns = (const float*)d_in[4];
    const float* lnb = (const float*)d_in[5];
    const float* Wd  = (const float*)d_in[6];
    const float* bd  = (const float*)d_in[7];
    float* out = (float*)d_out;

    // ws: hbHi 2x256x512 ushort (512 KB) | hbMid (512 KB) | bar (4 KB)
    ushort* hbHi  = (ushort*)d_ws;
    ushort* hbMid = hbHi + (size_t)2 * HTOT;
    unsigned* bar = (unsigned*)(hbMid + (size_t)2 * HTOT);

    hipMemsetAsync(bar, 0, 4096, stream);

    size_t smem = 140560;
    hipFuncSetAttribute((const void*)lstm_v8,
                        hipFuncAttributeMaxDynamicSharedMemorySize, (int)smem);

    void* args[] = { (void*)&x, (void*)&Wi, (void*)&Wh, (void*)&b, (void*)&lns,
                     (void*)&lnb, (void*)&Wd, (void*)&bd, (void*)&out,
                     (void*)&hbHi, (void*)&hbMid, (void*)&bar };
    hipLaunchCooperativeKernel((void*)lstm_v8, dim3(NWG), dim3(NTHR),
                               args, (unsigned int)smem, stream);
}